// Round 3
// baseline (228.286 us; speedup 1.0000x reference)
//
#include <hip/hip_runtime.h>

typedef short bf16x8 __attribute__((ext_vector_type(8)));
typedef float f32x4 __attribute__((ext_vector_type(4)));

#define NG   9
#define CIN  1152
#define IG1  128
#define OG1  512
#define IG2  512
#define OG2  128
#define KP   576      // padded K per g2 (9 runs * 64)
#define MT   32       // m-tile per block
#define MTOT 16384

__device__ __forceinline__ short f2bf(float f) {
    unsigned u = __float_as_uint(f);
    u += 0x7fff + ((u >> 16) & 1);   // RNE
    return (short)(u >> 16);
}

// ---- prep: W1 fp32 -> bf16 (layout kept: [9][512][128], k contiguous)
__global__ __launch_bounds__(256) void prep_w1(const float* __restrict__ w1, short* __restrict__ w1b) {
    int i = blockIdx.x * 256 + threadIdx.x;
    if (i < NG * OG1 * IG1) w1b[i] = f2bf(w1[i]);
}

// ---- prep: W2p[g2][o2][kp] permuted + zero-padded bf16
// kp = g1*64 + r  ->  o = olo(g1,g2)+r, j = 9*o + g1 - 512*g2 ; valid iff j < 512
__global__ __launch_bounds__(256) void prep_w2(const float* __restrict__ w2, short* __restrict__ w2p) {
    int i = blockIdx.x * 256 + threadIdx.x;
    if (i >= NG * OG2 * KP) return;
    int g2  = i / (OG2 * KP);
    int rem = i - g2 * (OG2 * KP);
    int o2  = rem / KP;
    int kp  = rem - o2 * KP;
    int g1 = kp >> 6, r = kp & 63;
    int olo = (512 * g2 - g1 + 8) / 9;           // ceil((512g2-g1)/9)
    int j = 9 * (olo + r) + g1 - 512 * g2;       // >= 0 by construction
    float v = (j < 512) ? w2[(g2 * OG2 + o2) * IG2 + j] : 0.0f;
    w2p[i] = f2bf(v);
}

// ---- fused: x -> L1(g1 slices) -> hardswish -> ht(LDS) -> L2 partial accum -> out
// 512 threads = 8 waves. Wave w: L1 o-slice [w*64,+64); L2 g2=w (128 cols) + g2=8 slice [w*16,+16).
__global__ __launch_bounds__(512) void fused(const float* __restrict__ x,
                                             const short* __restrict__ w1b, const float* __restrict__ b1,
                                             const short* __restrict__ w2p, const float* __restrict__ b2,
                                             float* __restrict__ out) {
    __shared__ __attribute__((aligned(16))) char smem[110592];
    short* xs = (short*)smem;             // [32 rows][144 granules of 8 bf16], XOR-swizzled, 73728 B
    short* ht = (short*)(smem + 73728);   // [32 rows][72 granules of 8 bf16],  XOR-swizzled, 36864 B
    float* outs = (float*)smem;           // epilogue overlay [16][1156] fp32 (73984 B, xs+ht dead)

    const int t = threadIdx.x;
    const int m0 = blockIdx.x * MT;
    const int w = t >> 6, lane = t & 63, lr = lane & 15, lg = lane >> 4;

    // zero ht once (pad slots must never be NaN; stale real values later are fine: W2p pads = 0)
    {
        int2 z = {0, 0};
#pragma unroll
        for (int i = 0; i < 9; ++i) *(int2*)(ht + (i * 512 + t) * 4) = z;
    }
    // stage x tile -> xs (bf16, swizzled); x read from HBM exactly once
#pragma unroll
    for (int i = 0; i < 9; ++i) {
        int f = i * 512 + t;                 // 0..4607 chunks of 8
        int row = f / 144, c8 = f - row * 144;
        const float* gp = x + (size_t)(m0 + row) * CIN + c8 * 8;
        float4 v0 = *(const float4*)gp;
        float4 v1 = *(const float4*)(gp + 4);
        bf16x8 s;
        s[0]=f2bf(v0.x); s[1]=f2bf(v0.y); s[2]=f2bf(v0.z); s[3]=f2bf(v0.w);
        s[4]=f2bf(v1.x); s[5]=f2bf(v1.y); s[6]=f2bf(v1.z); s[7]=f2bf(v1.w);
        *(bf16x8*)(xs + (row * 144 + (c8 ^ (row & 7))) * 8) = s;
    }

    f32x4 acc2[2][8];                       // g2=w, [mi][ni]
    f32x4 acc2b[2];                         // g2=8 slice, [mi]
#pragma unroll
    for (int mi = 0; mi < 2; ++mi) {
#pragma unroll
        for (int ni = 0; ni < 8; ++ni) acc2[mi][ni] = (f32x4){0.f,0.f,0.f,0.f};
        acc2b[mi] = (f32x4){0.f,0.f,0.f,0.f};
    }
    __syncthreads();

    for (int g1 = 0; g1 < NG; ++g1) {
        // ---- L1: swapped MFMA (A=W1 rows o, B=x rows m) -> C[o][m]
        f32x4 acc1[4][2];
#pragma unroll
        for (int oi = 0; oi < 4; ++oi)
#pragma unroll
            for (int mi = 0; mi < 2; ++mi) acc1[oi][mi] = (f32x4){0.f,0.f,0.f,0.f};
#pragma unroll
        for (int kf = 0; kf < 4; ++kf) {
            bf16x8 bx[2];
#pragma unroll
            for (int mi = 0; mi < 2; ++mi) {
                int row = mi * 16 + lr;
                bx[mi] = *(const bf16x8*)(xs + (row * 144 + ((g1 * 16 + kf * 4 + lg) ^ (row & 7))) * 8);
            }
#pragma unroll
            for (int oi = 0; oi < 4; ++oi) {
                bf16x8 af = *(const bf16x8*)(w1b + ((size_t)(g1 * OG1 + w * 64 + oi * 16 + lr) * IG1 + kf * 32 + lg * 8));
#pragma unroll
                for (int mi = 0; mi < 2; ++mi)
                    acc1[oi][mi] = __builtin_amdgcn_mfma_f32_16x16x32_bf16(af, bx[mi], acc1[oi][mi], 0, 0, 0);
            }
        }
        __syncthreads();   // previous L2 done reading ht
        // epilogue: bias + hardswish -> bf16 -> ht (swizzled b16 stores; lane holds 4 consecutive o)
#pragma unroll
        for (int oi = 0; oi < 4; ++oi) {
            int ob = w * 64 + oi * 16 + lg * 4;
            float4 bias = *(const float4*)(b1 + g1 * OG1 + ob);
#pragma unroll
            for (int q = 0; q < 4; ++q) {
                int o  = ob + q;
                int c  = 9 * o + g1;
                int g2 = c >> 9;
                int olo = (512 * g2 - g1 + 8) / 9;
                int hc = g2 * 64 + (o - olo);
#pragma unroll
                for (int mi = 0; mi < 2; ++mi) {
                    int m = mi * 16 + lr;
                    float v = acc1[oi][mi][q] + ((const float*)&bias)[q];
                    v = v * fminf(fmaxf(v + 3.0f, 0.0f), 6.0f) * (1.0f / 6.0f);
                    *(short*)((char*)ht + m * 1152 + (((hc >> 3) ^ (m & 7)) << 4) + (hc & 7) * 2) = f2bf(v);
                }
            }
        }
        __syncthreads();   // ht ready
        // ---- L2 partial: K-chunk g1*64, disjoint ht reads per wave
#pragma unroll
        for (int kf = 0; kf < 2; ++kf) {
            bf16x8 a_[2], a8_[2];
#pragma unroll
            for (int mi = 0; mi < 2; ++mi) {
                int m = mi * 16 + lr;
                a_[mi]  = *(const bf16x8*)((char*)ht + m * 1152 + (((w * 8 + kf * 4 + lg) ^ (m & 7)) << 4));
                a8_[mi] = *(const bf16x8*)((char*)ht + m * 1152 + (((64 + kf * 4 + lg) ^ (m & 7)) << 4));
            }
#pragma unroll
            for (int ni = 0; ni < 8; ++ni) {
                bf16x8 bfr = *(const bf16x8*)(w2p + (size_t)(w * 128 + ni * 16 + lr) * KP + g1 * 64 + kf * 32 + lg * 8);
#pragma unroll
                for (int mi = 0; mi < 2; ++mi)
                    acc2[mi][ni] = __builtin_amdgcn_mfma_f32_16x16x32_bf16(a_[mi], bfr, acc2[mi][ni], 0, 0, 0);
            }
            bf16x8 b8 = *(const bf16x8*)(w2p + (size_t)(8 * 128 + w * 16 + lr) * KP + g1 * 64 + kf * 32 + lg * 8);
#pragma unroll
            for (int mi = 0; mi < 2; ++mi)
                acc2b[mi] = __builtin_amdgcn_mfma_f32_16x16x32_bf16(a8_[mi], b8, acc2b[mi], 0, 0, 0);
        }
        // no barrier here: next L1 touches only xs; first ht write is after the next barrier
    }

    // ---- output epilogue: 2 half-tiles of 16 rows via LDS, fully-coalesced float4 rows
#pragma unroll
    for (int h = 0; h < 2; ++h) {
        __syncthreads();   // prior ht/outs reads done
#pragma unroll
        for (int ni = 0; ni < 8; ++ni) {
            float bias = b2[w * OG2 + ni * 16 + lr];
            int c = (ni * 16 + lr) * 9 + w;
#pragma unroll
            for (int q = 0; q < 4; ++q)
                outs[(lg * 4 + q) * 1156 + c] = acc2[h][ni][q] + bias;
        }
        {
            float bias8 = b2[8 * OG2 + w * 16 + lr];
            int c8 = (w * 16 + lr) * 9 + 8;
#pragma unroll
            for (int q = 0; q < 4; ++q)
                outs[(lg * 4 + q) * 1156 + c8] = acc2b[h][q] + bias8;
        }
        __syncthreads();
#pragma unroll
        for (int i = 0; i < 9; ++i) {
            int f4 = i * 512 + t;             // 0..4607 float4s
            int row = f4 / 288, c4 = f4 - row * 288;
            float4 v = *(const float4*)&outs[row * 1156 + c4 * 4];
            *(float4*)&out[(size_t)(m0 + h * 16 + row) * CIN + c4 * 4] = v;
        }
    }
}

extern "C" void kernel_launch(void* const* d_in, const int* in_sizes, int n_in,
                              void* d_out, int out_size, void* d_ws, size_t ws_size,
                              hipStream_t stream) {
    const float* x  = (const float*)d_in[0];
    const float* w1 = (const float*)d_in[1];
    const float* b1 = (const float*)d_in[2];
    const float* w2 = (const float*)d_in[3];
    const float* b2 = (const float*)d_in[4];
    float* out = (float*)d_out;

    short* w1b = (short*)d_ws;                                          // 1,179,648 B
    short* w2p = (short*)((char*)d_ws + (size_t)NG * OG1 * IG1 * 2);    // 1,327,104 B

    prep_w1<<<(NG * OG1 * IG1 + 255) / 256, 256, 0, stream>>>(w1, w1b);
    prep_w2<<<(NG * OG2 * KP + 255) / 256, 256, 0, stream>>>(w2, w2p);
    fused<<<MTOT / MT, 512, 0, stream>>>(x, w1b, b1, w2p, b2, out);
}